// Round 2
// baseline (3038.274 us; speedup 1.0000x reference)
//
#include <hip/hip_runtime.h>

typedef unsigned int u32;
typedef unsigned short u16;
typedef __attribute__((ext_vector_type(4))) u32 u32x4;
typedef __attribute__((ext_vector_type(4))) u16 u16x4;
typedef __attribute__((ext_vector_type(8))) short bf16x8;
typedef __attribute__((ext_vector_type(4))) float f32x4;
typedef __attribute__((ext_vector_type(2))) _Float16 h2f;

__device__ __forceinline__ u16 f2bf(float x){
  u32 u = __builtin_bit_cast(u32, x);
  u = (u + 0x7fffu + ((u >> 16) & 1u)) >> 16;
  return (u16)u;
}
__device__ __forceinline__ u16 f2h(float x){
  _Float16 h = (_Float16)x;
  return __builtin_bit_cast(u16, h);
}
__device__ __forceinline__ h2f as_h2(u32 v){ return __builtin_bit_cast(h2f, v); }
__device__ __forceinline__ float sigf(float x){ return 1.0f/(1.0f + __expf(-x)); }
__device__ __forceinline__ float tanh_f(float x){ float e = __expf(2.0f*x); return 1.0f - 2.0f/(e + 1.0f); }

__device__ __forceinline__ float dot2acc(u32 a, u32 b, float acc){
#if __has_builtin(__builtin_amdgcn_fdot2)
  return __builtin_amdgcn_fdot2(as_h2(a), as_h2(b), acc, false);
#else
  h2f ha = as_h2(a), hb = as_h2(b);
  return acc + (float)ha[0]*(float)hb[0] + (float)ha[1]*(float)hb[1];
#endif
}

// ---------------- conversion kernels ----------------

// x (1024 x 50001) f32 -> xb (1024 x 50176) bf16, zero-pad cols [50000,50176)
__global__ void conv_x(const float* __restrict__ x, u16* __restrict__ xb){
  int col4 = (blockIdx.x*256 + threadIdx.x)*4;   // grid (49, 1024)
  int row  = blockIdx.y;
  const float* src = x + (long)row*50001 + col4;
  u16x4 v;
  if (col4 < 50000) { v[0]=f2bf(src[0]); v[1]=f2bf(src[1]); v[2]=f2bf(src[2]); v[3]=f2bf(src[3]); }
  else { v[0]=0; v[1]=0; v[2]=0; v[3]=0; }
  *(u16x4*)(xb + (long)row*50176 + col4) = v;
}

// enc_w1 (512 x 50000) f32 -> w1b (512 x 50176) bf16 padded
__global__ void conv_w1(const float* __restrict__ w, u16* __restrict__ wb){
  int col4 = (blockIdx.x*256 + threadIdx.x)*4;   // grid (49, 512)
  int row  = blockIdx.y;
  const float* src = w + (long)row*50000 + col4;
  u16x4 v;
  if (col4 < 50000) { v[0]=f2bf(src[0]); v[1]=f2bf(src[1]); v[2]=f2bf(src[2]); v[3]=f2bf(src[3]); }
  else { v[0]=0; v[1]=0; v[2]=0; v[3]=0; }
  *(u16x4*)(wb + (long)row*50176 + col4) = v;
}

// dec_w2 (50000 x 512) f32 -> w2db (50048 x 512) bf16, zero rows >= 50000
__global__ void conv_w2d(const float* __restrict__ w, u16* __restrict__ wb){
  int col = blockIdx.x*256 + threadIdx.x;        // grid (2, 50048)
  int row = blockIdx.y;
  float v = (row < 50000) ? w[(long)row*512 + col] : 0.0f;
  wb[(long)row*512 + col] = f2bf(v);
}

// enc_w2 (256x512), dec_w1 (512x256), gate W_w stacked -> bf16
__global__ void conv_misc(const float* __restrict__ enc_w2, const float* __restrict__ dec_w1,
                          const float* __restrict__ dw, const float* __restrict__ iw,
                          const float* __restrict__ ow, const float* __restrict__ cw,
                          u16* __restrict__ w2eb, u16* __restrict__ wd1b, u16* __restrict__ wgb){
  int idx = blockIdx.x*256 + threadIdx.x;        // grid 2048
  if (idx < 131072) {
    w2eb[idx] = f2bf(enc_w2[idx]);
  } else if (idx < 262144) {
    int i = idx - 131072;
    wd1b[i] = f2bf(dec_w1[i]);
  } else {
    int i = idx - 262144;                        // 262144 elems: wgb[o][k], o = g*256+e
    int o = i >> 8, k = i & 255;
    int g = o >> 8, e = o & 255;
    const float* W = (g==0) ? dw : (g==1) ? iw : (g==2) ? ow : cw;
    wgb[i] = f2bf(W[e*256 + k]);
  }
}

// combined gate biases: bws[o] = u_b[e] + w_b[e]
__global__ void pack_bias(const float* dub, const float* dwb, const float* iub, const float* iwb,
                          const float* oub, const float* owb, const float* cub, const float* cwb,
                          float* __restrict__ bws){
  int o = blockIdx.x*256 + threadIdx.x;          // grid 4
  int g = o >> 8, e = o & 255;
  float v;
  if      (g==0) v = dub[e] + dwb[e];
  else if (g==1) v = iub[e] + iwb[e];
  else if (g==2) v = oub[e] + owb[e];
  else           v = cub[e] + cwb[e];
  bws[o] = v;
}

// Pack recurrent U matrices into the scan's register / LDS layouts (f16).
// Thread t (of 512): q=t>>2, c=t&3; owns outputs o = q*8+j (j<8), k in [c*64, c*64+64).
// k-cols [0,48) -> upack[(j*24 + kk/2)*512 + t] as f16x2; k-cols [48,64) -> utail image.
__global__ void pack_u(const float* du, const float* iu, const float* ou, const float* cu,
                       u32* __restrict__ upack, u16* __restrict__ utail_img){
  int t = threadIdx.x;                           // 1 block, 512 threads
  int c = t & 3, q = t >> 2;
  for (int j = 0; j < 8; ++j) {
    int o = q*8 + j;
    int g = o >> 8, e = o & 255;
    const float* U = (g==0) ? du : (g==1) ? iu : (g==2) ? ou : cu;
    const float* row = U + e*256 + c*64;
    for (int kk = 0; kk < 48; kk += 2) {
      u32 lo = f2h(row[kk]);
      u32 hi = f2h(row[kk+1]);
      upack[(j*24 + (kk>>1))*512 + t] = lo | (hi << 16);
    }
    for (int kk = 48; kk < 64; ++kk) {
      int s = (kk-48) >> 3, b = (kk-48) & 7;
      utail_img[(size_t)((j*2+s)*512 + t)*8 + b] = f2h(row[kk]);
    }
  }
}

// ---------------- MFMA GEMM: C = A @ B^T, A[M][K] bf16, B[N][K] bf16 ----------------
// EPI: 0 = store f32 partial at Cf + z*1024*ldc (split-K)
//      1 = bias + relu -> bf16 Cb
//      2 = bias -> f32 Cf
//      3 = bias + sigmoid -> f32 Cf with col < nGuard
template<int EPI>
__global__ __launch_bounds__(256)
void gemm_bt(const u16* __restrict__ A, const u16* __restrict__ B,
             const float* __restrict__ bias, float* __restrict__ Cf, u16* __restrict__ Cb,
             int lda, int ldb, int ldc, int kiters, int nGuard){
  __shared__ u16 As[128*32];
  __shared__ u16 Bs[128*32];
  const int tid = threadIdx.x;
  const int l = tid & 63;
  const int w = tid >> 6;
  const int wr = w >> 1, wc = w & 1;             // 2x2 wave grid, 64x64 per wave
  const long kchunk = (long)blockIdx.z * kiters * 32;
  const u16* Ab = A + (long)blockIdx.x*128*lda + kchunk;
  const u16* Bb = B + (long)blockIdx.y*128*ldb + kchunk;
  f32x4 acc[4][4];
#pragma unroll
  for (int m=0;m<4;m++)
#pragma unroll
    for (int n=0;n<4;n++) acc[m][n] = (f32x4){0.f,0.f,0.f,0.f};

  const int lr = l & 15, lk = l >> 4;
  for (int it = 0; it < kiters; ++it) {
    // stage 128x32 tiles of A and B (each thread: 2 slots of 8 bf16 for each)
    {
      int s = tid;
      int row = s >> 2, kg = s & 3;
      u32x4 va = *(const u32x4*)(Ab + (long)row*lda + (long)it*32 + kg*8);
      u32x4 vb = *(const u32x4*)(Bb + (long)row*ldb + (long)it*32 + kg*8);
      int sw = ((kg + row) & 3) * 8;
      *(u32x4*)&As[row*32 + sw] = va;
      *(u32x4*)&Bs[row*32 + sw] = vb;
      s = tid + 256;
      row = s >> 2; kg = s & 3;
      va = *(const u32x4*)(Ab + (long)row*lda + (long)it*32 + kg*8);
      vb = *(const u32x4*)(Bb + (long)row*ldb + (long)it*32 + kg*8);
      sw = ((kg + row) & 3) * 8;
      *(u32x4*)&As[row*32 + sw] = va;
      *(u32x4*)&Bs[row*32 + sw] = vb;
    }
    __syncthreads();
    bf16x8 af[4], bfr[4];
#pragma unroll
    for (int m=0;m<4;m++) {
      int row = wr*64 + m*16 + lr;
      af[m] = *(const bf16x8*)&As[row*32 + (((lk + row)&3)*8)];
    }
#pragma unroll
    for (int n=0;n<4;n++) {
      int row = wc*64 + n*16 + lr;
      bfr[n] = *(const bf16x8*)&Bs[row*32 + (((lk + row)&3)*8)];
    }
#pragma unroll
    for (int m=0;m<4;m++)
#pragma unroll
      for (int n=0;n<4;n++)
        acc[m][n] = __builtin_amdgcn_mfma_f32_16x16x32_bf16(af[m], bfr[n], acc[m][n], 0, 0, 0);
    __syncthreads();
  }
  // epilogue: C row = (l>>4)*4 + v, col = l&15 within each 16x16 frag
#pragma unroll
  for (int m=0;m<4;m++) {
#pragma unroll
    for (int n=0;n<4;n++) {
#pragma unroll
      for (int v=0;v<4;v++) {
        int r  = wr*64 + m*16 + lk*4 + v;
        int cn = wc*64 + n*16 + lr;
        long gr = (long)blockIdx.x*128 + r;
        long gc = (long)blockIdx.y*128 + cn;
        float val = acc[m][n][v];
        if (EPI == 0) {
          Cf[((long)blockIdx.z*1024 + gr)*ldc + gc] = val;
        } else if (EPI == 1) {
          float y = val + bias[gc];
          y = y > 0.f ? y : 0.f;
          Cb[gr*ldc + gc] = f2bf(y);
        } else if (EPI == 2) {
          Cf[gr*ldc + gc] = val + bias[gc];
        } else if (EPI == 3) {
          if (gc < nGuard) Cf[gr*ldc + gc] = sigf(val + bias[gc]);
        }
      }
    }
  }
}

// sum split-K partials + bias + relu -> bf16 h1b
__global__ void reduce1(const float* __restrict__ P, const float* __restrict__ b1,
                        u16* __restrict__ h1b){
  int idx = blockIdx.x*256 + threadIdx.x;        // grid 2048 -> 524288 = 1024*512
  float s = b1[idx & 511];
#pragma unroll
  for (int kc = 0; kc < 32; ++kc) s += P[(long)kc*524288 + idx];
  h1b[idx] = f2bf(s > 0.f ? s : 0.f);
}

// ---------------- sequential scan: 1 block, 512 threads ----------------
// Thread t: q=t>>2 (output group, 8 outputs o=q*8+j), c=t&3 (K-chunk of 64).
// U: k-cols [0,48) in 192 VGPRs (f16x2), k-cols [48,64) in LDS (128 KB f16).
// hist (LAG 50) lives in f16-pair registers of threads t<256 (one per element e).
__global__ __launch_bounds__(512)
void scan_kernel(const u32* __restrict__ upack, const u32x4* __restrict__ utail_img,
                 const float* __restrict__ xw, u16* __restrict__ hsb){
  __shared__ u16   utail[65536];                 // 131072 B  (static LDS: total 135,680 B < 160 KiB)
  __shared__ float preact[1024];                 // 4096 B    (index o = g*256+e)
  __shared__ u16   hlds[256];                    // 512 B     (h as f16)
  const int t = threadIdx.x;
  const int c = t & 3;
  const int q = t >> 2;

  u32 ur[192];
#pragma unroll
  for (int i = 0; i < 192; ++i) ur[i] = upack[i*512 + t];
#pragma unroll
  for (int i = 0; i < 16; ++i)
    ((u32x4*)utail)[i*512 + t] = utail_img[i*512 + t];

  u32 hq[25];
#pragma unroll
  for (int i = 0; i < 25; ++i) hq[i] = 0;
  if (t < 256) hlds[t] = 0;
  __syncthreads();

  for (int st = 0; st < 1024; ++st) {
    float xw0=0.f, xw1=0.f, xw2=0.f, xw3=0.f;
    if (t < 256) {                               // prefetch; consumed after phase A
      xw0 = xw[st*1024 + t];
      xw1 = xw[st*1024 + 256 + t];
      xw2 = xw[st*1024 + 512 + t];
      xw3 = xw[st*1024 + 768 + t];
    }
    // ---- phase A: preact[o] = sum_k h[k] * U[o][k] (this thread: k in [c*64, c*64+64)) ----
    float acc[8] = {0,0,0,0,0,0,0,0};
#pragma unroll
    for (int b = 0; b < 6; ++b) {                // register-resident k-cols [0,48)
      u32x4 hb = *(const u32x4*)&hlds[c*64 + b*8];
#pragma unroll
      for (int j = 0; j < 8; ++j)
#pragma unroll
        for (int p = 0; p < 4; ++p)
          acc[j] = dot2acc(ur[j*24 + b*4 + p], hb[p], acc[j]);
    }
#pragma unroll
    for (int s = 0; s < 2; ++s) {                // LDS-resident k-cols [48,64)
      u32x4 hb = *(const u32x4*)&hlds[c*64 + 48 + s*8];
#pragma unroll
      for (int j = 0; j < 8; ++j) {
        u32x4 ut = *(const u32x4*)&utail[(size_t)((j*2+s)*512 + t)*8];
#pragma unroll
        for (int p = 0; p < 4; ++p)
          acc[j] = dot2acc(ut[p], hb[p], acc[j]);
      }
    }
#pragma unroll
    for (int j = 0; j < 8; ++j) {                // reduce over the 4 K-chunks (lanes l^1, l^2)
      acc[j] += __shfl_xor(acc[j], 1);
      acc[j] += __shfl_xor(acc[j], 2);
    }
    // all 4 lanes of a group hold identical sums; redundant same-value writes are benign
    *(f32x4*)&preact[q*8]     = (f32x4){acc[0], acc[1], acc[2], acc[3]};
    *(f32x4*)&preact[q*8 + 4] = (f32x4){acc[4], acc[5], acc[6], acc[7]};
    __syncthreads();

    // ---- phase B: gates + lag-memory + h update (threads 0..255, e = t) ----
    if (t < 256) {
      float pd = preact[t]       + xw0;
      float pi = preact[256 + t] + xw1;
      float po = preact[512 + t] + xw2;
      float pc = preact[768 + t] + xw3;
      float d  = 0.5f * sigf(pd);
      float gi = sigf(pi);
      float go = sigf(po);
      float ct = tanh_f(pc);
      float cur = gi * ct;
      // mem = sum_k w_k * hist_k ; w_0 = 1, w_k = w_{k-1} * (d+k-1)/k  (== exp(gammaln ratio))
      float mem = cur;
      float wk = 1.0f;
#pragma unroll
      for (int k = 1; k < 50; ++k) {
        wk *= (d + (float)(k-1)) * (1.0f/(float)k);
        u32 pair = hq[(k-1) >> 1];
        float hv = ((k-1) & 1) ? (float)as_h2(pair)[1] : (float)as_h2(pair)[0];
        mem += wk * hv;
      }
      float hnew = go * tanh_f(mem);
      // shift history by one (packed f16 pairs), insert cur at age 0
#pragma unroll
      for (int i = 24; i >= 1; --i) hq[i] = (hq[i] << 16) | (hq[i-1] >> 16);
      hq[0] = (hq[0] << 16) | (u32)f2h(cur);
      hlds[t] = f2h(hnew);
      hsb[st*256 + t] = f2bf(hnew);
    }
    __syncthreads();
  }
}

// ---------------- launcher ----------------
extern "C" void kernel_launch(void* const* d_in, const int* in_sizes, int n_in,
                              void* d_out, int out_size, void* d_ws, size_t ws_size,
                              hipStream_t stream){
  const float* x      = (const float*)d_in[0];
  const float* enc_w1 = (const float*)d_in[1];
  const float* enc_b1 = (const float*)d_in[2];
  const float* enc_w2 = (const float*)d_in[3];
  const float* enc_b2 = (const float*)d_in[4];
  const float* d_u_w  = (const float*)d_in[5];  const float* d_u_b = (const float*)d_in[6];
  const float* d_w_w  = (const float*)d_in[7];  const float* d_w_b = (const float*)d_in[8];
  const float* i_u_w  = (const float*)d_in[9];  const float* i_u_b = (const float*)d_in[10];
  const float* i_w_w  = (const float*)d_in[11]; const float* i_w_b = (const float*)d_in[12];
  const float* o_u_w  = (const float*)d_in[13]; const float* o_u_b = (const float*)d_in[14];
  const float* o_w_w  = (const float*)d_in[15]; const float* o_w_b = (const float*)d_in[16];
  const float* c_u_w  = (const float*)d_in[17]; const float* c_u_b = (const float*)d_in[18];
  const float* c_w_w  = (const float*)d_in[19]; const float* c_w_b = (const float*)d_in[20];
  const float* dec_w1 = (const float*)d_in[21]; const float* dec_b1 = (const float*)d_in[22];
  const float* dec_w2 = (const float*)d_in[23]; const float* dec_b2 = (const float*)d_in[24];

  char* ws = (char*)d_ws;
  // ws layout (total ~214.3 MB)
  u16*   xb     = (u16*)(ws + 0L);                 // 1024*50176*2 = 102,760,448
  u16*   w1b    = (u16*)(ws + 102760448L);         // 512*50176*2  =  51,380,224
  u16*   w2db   = (u16*)(ws + 154140672L);         // 50048*512*2  =  51,249,152
  u16*   h1b    = (u16*)(ws + 205389824L);         // 1024*512*2
  u16*   e_b    = (u16*)(ws + 206438400L);         // 1024*256*2
  u16*   wgb    = (u16*)(ws + 206962688L);         // 1024*256*2
  u16*   w2eb   = (u16*)(ws + 207486976L);         // 256*512*2
  u16*   wd1b   = (u16*)(ws + 207749120L);         // 512*256*2
  u16*   d1b    = (u16*)(ws + 208011264L);         // 1024*512*2
  u16*   hsb    = (u16*)(ws + 209059840L);         // 1024*256*2
  float* xw     = (float*)(ws + 209584128L);       // 1024*1024*4
  float* bws    = (float*)(ws + 213778432L);       // 1024*4
  u32*   upack  = (u32*)(ws + 213782528L);         // 192*512*4
  u16*   utailI = (u16*)(ws + 214175744L);         // 16*512*16
  float* out    = (float*)d_out;
  float* P      = (float*)d_out;                   // split-K partials (67 MB) reuse d_out

  // converts / packs
  conv_x   <<<dim3(49,1024), 256, 0, stream>>>(x, xb);
  conv_w1  <<<dim3(49,512),  256, 0, stream>>>(enc_w1, w1b);
  conv_w2d <<<dim3(2,50048), 256, 0, stream>>>(dec_w2, w2db);
  conv_misc<<<2048, 256, 0, stream>>>(enc_w2, dec_w1, d_w_w, i_w_w, o_w_w, c_w_w, w2eb, wd1b, wgb);
  pack_bias<<<4, 256, 0, stream>>>(d_u_b, d_w_b, i_u_b, i_w_b, o_u_b, o_w_b, c_u_b, c_w_b, bws);
  pack_u   <<<1, 512, 0, stream>>>(d_u_w, i_u_w, o_u_w, c_u_w, upack, utailI);

  // encoder: h1 = relu(x @ w1^T + b1)  -- split-K=32 over Kpad=50176
  gemm_bt<0><<<dim3(8,4,32), 256, 0, stream>>>(xb, w1b, nullptr, P, nullptr, 50176, 50176, 512, 49, 0);
  reduce1<<<2048, 256, 0, stream>>>(P, enc_b1, h1b);
  // e = relu(h1 @ enc_w2^T + b2)
  gemm_bt<1><<<dim3(8,2,1), 256, 0, stream>>>(h1b, w2eb, enc_b2, nullptr, e_b, 512, 512, 256, 16, 0);
  // xw[t][g*256+e] = e_t @ Wg^T + (w_b + u_b)
  gemm_bt<2><<<dim3(8,8,1), 256, 0, stream>>>(e_b, wgb, bws, xw, nullptr, 256, 256, 1024, 8, 0);
  // sequential recurrence (static LDS; no hipFuncSetAttribute needed)
  scan_kernel<<<1, 512, 0, stream>>>(upack, (const u32x4*)utailI, xw, hsb);
  // decoder
  gemm_bt<1><<<dim3(8,4,1), 256, 0, stream>>>(hsb, wd1b, dec_b1, nullptr, d1b, 256, 256, 512, 8, 0);
  gemm_bt<3><<<dim3(8,391,1), 256, 0, stream>>>(d1b, w2db, dec_b2, out, nullptr, 512, 512, 50000, 16, 50000);
}